// Round 1
// baseline (818.828 us; speedup 1.0000x reference)
//
#include <hip/hip_runtime.h>

#define D_OUT 4096
#define D_IN  4096
#define RANK  64
#define NNZ   1000000
#define MTOT  8192   // 4*2048
#define KDIM  4096
#define NDIM  4096

typedef __bf16 bf16_t;
typedef __bf16 bf16x8 __attribute__((ext_vector_type(8)));
typedef float  f32x4  __attribute__((ext_vector_type(4)));

// ---------------- kernel 1: W_eff = W_inner + A @ Bmat ----------------
// Block computes a 64(o) x 256(d) tile. A-tile (64x64) in LDS, Bmat row
// broadcast from L2, 64 accumulators/thread for register reuse.
__global__ __launch_bounds__(256) void build_weff_kernel(
    const float* __restrict__ W, const float* __restrict__ A,
    const float* __restrict__ B, float* __restrict__ out) {
  __shared__ float sA[64 * 64];
  const int o0 = blockIdx.y * 64;
  const int d  = blockIdx.x * 256 + threadIdx.x;
  // A rows o0..o0+63 are contiguous: flat [o0*64, o0*64+4096)
  #pragma unroll
  for (int i = 0; i < 16; ++i)
    sA[threadIdx.x + i * 256] = A[(size_t)o0 * 64 + threadIdx.x + i * 256];
  __syncthreads();

  float acc[64];
  #pragma unroll
  for (int o = 0; o < 64; ++o) acc[o] = 0.f;

  for (int r = 0; r < 64; ++r) {
    float bv = B[(size_t)r * D_IN + d];
    #pragma unroll
    for (int o = 0; o < 64; ++o) acc[o] += sA[o * 64 + r] * bv;
  }

  #pragma unroll
  for (int o = 0; o < 64; ++o) {
    size_t idx = (size_t)(o0 + o) * D_IN + d;
    out[idx] = W[idx] + acc[o];
  }
}

// ---------------- kernel 2: scatter-add sparse COO into W_eff ----------------
__global__ __launch_bounds__(256) void scatter_sp_kernel(
    const float* __restrict__ vals, const int* __restrict__ idx,
    float* __restrict__ weff) {
  int i = blockIdx.x * 256 + threadIdx.x;
  if (i < NNZ) {
    int r = idx[i];
    int c = idx[NNZ + i];
    atomicAdd(&weff[(size_t)r * D_IN + c], vals[i]);
  }
}

// ---------------- kernel 3: fp32 -> bf16 cast (8 elems/thread) ----------------
__global__ __launch_bounds__(256) void cvt_bf16_kernel(
    const float* __restrict__ in, bf16_t* __restrict__ out, int n8) {
  int i = blockIdx.x * 256 + threadIdx.x;
  if (i >= n8) return;
  const f32x4* p = (const f32x4*)in + (size_t)i * 2;
  f32x4 a = p[0], b = p[1];
  bf16x8 o;
  o[0] = (bf16_t)a[0]; o[1] = (bf16_t)a[1]; o[2] = (bf16_t)a[2]; o[3] = (bf16_t)a[3];
  o[4] = (bf16_t)b[0]; o[5] = (bf16_t)b[1]; o[6] = (bf16_t)b[2]; o[7] = (bf16_t)b[3];
  *((bf16x8*)out + i) = o;
}

// ---------------- kernel 4: out[M][N] = Xb[M][K] @ Wb[N][K]^T ----------------
// m97-ladder structure: 128x128 block tile, 4 waves in 2x2, each wave 64x64
// (4x4 grid of 16x16x32 bf16 MFMA), BK=64, global_load_lds width 16,
// unpadded LDS tiles laid out in lane order.
__global__ __launch_bounds__(256) void gemm_bt_kernel(
    const bf16_t* __restrict__ Xb, const bf16_t* __restrict__ Wb,
    float* __restrict__ out) {
  __shared__ bf16_t lA[128 * 64];   // 16 KB
  __shared__ bf16_t lB[128 * 64];   // 16 KB

  const int t    = threadIdx.x;
  const int w    = t >> 6;
  const int lane = t & 63;
  const int m0 = blockIdx.y * 128;
  const int n0 = blockIdx.x * 128;
  const int wm = (w >> 1) * 64;
  const int wn = (w & 1) * 64;
  const int lr = lane & 15;   // row within 16 (frag), col of C
  const int lq = lane >> 4;   // quad

  f32x4 acc[4][4] = {};

  for (int k0 = 0; k0 < KDIM; k0 += 64) {
    // ---- stage 128x64 A-tile and B-tile to LDS (16 B / lane / issue) ----
    #pragma unroll
    for (int j = 0; j < 4; ++j) {
      int f   = j * 256 + t;        // 0..1023, lane-contiguous within a wave
      int row = f >> 3;             // 0..127
      int kc  = (f & 7) << 3;       // 0..56 bf16 elems
      const bf16_t* ga = Xb + (size_t)(m0 + row) * KDIM + k0 + kc;
      const bf16_t* gb = Wb + (size_t)(n0 + row) * KDIM + k0 + kc;
      __builtin_amdgcn_global_load_lds(
          (const __attribute__((address_space(1))) void*)(const void*)ga,
          (__attribute__((address_space(3))) void*)(void*)&lA[f * 8], 16, 0, 0);
      __builtin_amdgcn_global_load_lds(
          (const __attribute__((address_space(1))) void*)(const void*)gb,
          (__attribute__((address_space(3))) void*)(void*)&lB[f * 8], 16, 0, 0);
    }
    __syncthreads();

    // ---- compute: 2 k-steps of 32, 16 MFMAs each ----
    #pragma unroll
    for (int kk = 0; kk < 64; kk += 32) {
      bf16x8 af[4], bfr[4];
      #pragma unroll
      for (int i = 0; i < 4; ++i)
        af[i] = *(const bf16x8*)&lA[(wm + i * 16 + lr) * 64 + kk + lq * 8];
      #pragma unroll
      for (int j = 0; j < 4; ++j)
        bfr[j] = *(const bf16x8*)&lB[(wn + j * 16 + lr) * 64 + kk + lq * 8];
      #pragma unroll
      for (int i = 0; i < 4; ++i)
        #pragma unroll
        for (int j = 0; j < 4; ++j)
          acc[i][j] = __builtin_amdgcn_mfma_f32_16x16x32_bf16(
              af[i], bfr[j], acc[i][j], 0, 0, 0);
    }
    __syncthreads();
  }

  // ---- epilogue: C/D mapping col=lane&15, row=(lane>>4)*4+reg ----
  #pragma unroll
  for (int i = 0; i < 4; ++i)
    #pragma unroll
    for (int j = 0; j < 4; ++j)
      #pragma unroll
      for (int rr = 0; rr < 4; ++rr) {
        int mm = m0 + wm + i * 16 + lq * 4 + rr;
        int nn = n0 + wn + j * 16 + lr;
        out[(size_t)mm * NDIM + nn] = acc[i][j][rr];
      }
}

extern "C" void kernel_launch(void* const* d_in, const int* in_sizes, int n_in,
                              void* d_out, int out_size, void* d_ws, size_t ws_size,
                              hipStream_t stream) {
  const float* x  = (const float*)d_in[0];   // [4,2048,4096] fp32
  const float* W  = (const float*)d_in[1];   // [4096,4096]
  const float* A  = (const float*)d_in[2];   // [4096,64]
  const float* B  = (const float*)d_in[3];   // [64,4096]
  const float* sv = (const float*)d_in[4];   // [1e6]
  const int*   si = (const int*)d_in[5];     // [2,1e6] int32 (jax x64 disabled)
  float* out = (float*)d_out;

  // workspace layout: weff f32 (64MB) | weff bf16 (32MB) | x bf16 (64MB)
  float*  weff  = (float*)d_ws;
  bf16_t* weffb = (bf16_t*)(weff + (size_t)D_OUT * D_IN);
  bf16_t* xb    = weffb + (size_t)D_OUT * D_IN;

  build_weff_kernel<<<dim3(D_IN / 256, D_OUT / 64), 256, 0, stream>>>(W, A, B, weff);
  scatter_sp_kernel<<<(NNZ + 255) / 256, 256, 0, stream>>>(sv, si, weff);
  cvt_bf16_kernel<<<(D_OUT * D_IN / 8) / 256, 256, 0, stream>>>(weff, weffb, D_OUT * D_IN / 8);
  cvt_bf16_kernel<<<(MTOT * KDIM / 8) / 256, 256, 0, stream>>>(x, xb, MTOT * KDIM / 8);
  gemm_bt_kernel<<<dim3(NDIM / 128, MTOT / 128), 256, 0, stream>>>(xb, weffb, out);
}

// Round 2
// 740.034 us; speedup vs baseline: 1.1065x; 1.1065x over previous
//
#include <hip/hip_runtime.h>

#define D_OUT 4096
#define D_IN  4096
#define RANK  64
#define NNZ   1000000
#define MTOT  8192   // 4*2048
#define KDIM  4096
#define NDIM  4096

typedef __bf16 bf16_t;
typedef __bf16 bf16x8 __attribute__((ext_vector_type(8)));
typedef float  f32x4  __attribute__((ext_vector_type(4)));

// ---------------- kernel 0: zero the sparse-accumulation buffer ----------------
__global__ __launch_bounds__(256) void zero_f32_kernel(float* __restrict__ p, int n4) {
  int stride = gridDim.x * 256;
  for (int i = blockIdx.x * 256 + threadIdx.x; i < n4; i += stride) {
    f32x4 z = {0.f, 0.f, 0.f, 0.f};
    *((f32x4*)p + i) = z;
  }
}

// ---------------- kernel 1: scatter-add sparse COO into S ----------------
__global__ __launch_bounds__(256) void scatter_sp_kernel(
    const float* __restrict__ vals, const int* __restrict__ idx,
    float* __restrict__ S) {
  int i = blockIdx.x * 256 + threadIdx.x;
  if (i < NNZ) {
    int r = idx[i];
    int c = idx[NNZ + i];
    atomicAdd(&S[(size_t)r * D_IN + c], vals[i]);
  }
}

// ---------------- kernel 2: weffb = bf16(W + A@Bmat + S) ----------------
// Block computes 64(o) x 256(d). A-tile (64x64) in LDS; Bmat rows stream
// from L2; 64 fp32 accumulators/thread.
__global__ __launch_bounds__(256) void build_weff_fused_kernel(
    const float* __restrict__ W, const float* __restrict__ A,
    const float* __restrict__ B, const float* __restrict__ S,
    bf16_t* __restrict__ outb) {
  __shared__ float sA[64 * 64];
  const int o0 = blockIdx.y * 64;
  const int d  = blockIdx.x * 256 + threadIdx.x;
  #pragma unroll
  for (int i = 0; i < 16; ++i)
    sA[threadIdx.x + i * 256] = A[(size_t)o0 * 64 + threadIdx.x + i * 256];
  __syncthreads();

  float acc[64];
  #pragma unroll
  for (int o = 0; o < 64; ++o) acc[o] = 0.f;

  for (int r = 0; r < 64; ++r) {
    float bv = B[(size_t)r * D_IN + d];
    #pragma unroll
    for (int o = 0; o < 64; ++o) acc[o] += sA[o * 64 + r] * bv;
  }

  #pragma unroll
  for (int o = 0; o < 64; ++o) {
    size_t idx = (size_t)(o0 + o) * D_IN + d;
    outb[idx] = (bf16_t)(W[idx] + S[idx] + acc[o]);
  }
}

// ---------------- kernel 3: fp32 -> bf16 cast (8 elems/thread) ----------------
__global__ __launch_bounds__(256) void cvt_bf16_kernel(
    const float* __restrict__ in, bf16_t* __restrict__ out, int n8) {
  int i = blockIdx.x * 256 + threadIdx.x;
  if (i >= n8) return;
  const f32x4* p = (const f32x4*)in + (size_t)i * 2;
  f32x4 a = p[0], b = p[1];
  bf16x8 o;
  o[0] = (bf16_t)a[0]; o[1] = (bf16_t)a[1]; o[2] = (bf16_t)a[2]; o[3] = (bf16_t)a[3];
  o[4] = (bf16_t)b[0]; o[5] = (bf16_t)b[1]; o[6] = (bf16_t)b[2]; o[7] = (bf16_t)b[3];
  *((bf16x8*)out + i) = o;
}

// ---------------- kernel 4: out[M][N] = Xb[M][K] @ Wb[N][K]^T ----------------
// m97 structure + XOR-swizzled LDS k-chunks: lane f stages global chunk
// (f&7)^((f>>3)&7) so fragment ds_read_b128 start-banks cover all 32 banks
// (was: banks 0-15 only -> 16-way serialization, 1e8 conflict cycles).
__global__ __launch_bounds__(256) void gemm_bt_kernel(
    const bf16_t* __restrict__ Xb, const bf16_t* __restrict__ Wb,
    float* __restrict__ out) {
  __shared__ bf16_t lA[128 * 64];   // 16 KB
  __shared__ bf16_t lB[128 * 64];   // 16 KB

  const int t    = threadIdx.x;
  const int w    = t >> 6;
  const int lane = t & 63;
  const int m0 = blockIdx.y * 128;
  const int n0 = blockIdx.x * 128;
  const int wm = (w >> 1) * 64;
  const int wn = (w & 1) * 64;
  const int lr = lane & 15;   // fragment row / C col
  const int lq = lane >> 4;   // quad
  const int h  = lr & 7;      // swizzle key for this lane's fragment rows

  f32x4 acc[4][4] = {};

  for (int k0 = 0; k0 < KDIM; k0 += 64) {
    // ---- stage 128x64 A/B tiles, 16 B/lane, XOR-swizzled source chunk ----
    #pragma unroll
    for (int j = 0; j < 4; ++j) {
      int f   = j * 256 + t;                  // 0..1023
      int row = f >> 3;                       // 0..127
      int kc  = (((f & 7) ^ (row & 7)) << 3); // swizzled k-chunk, elems
      const bf16_t* ga = Xb + (size_t)(m0 + row) * KDIM + k0 + kc;
      const bf16_t* gb = Wb + (size_t)(n0 + row) * KDIM + k0 + kc;
      __builtin_amdgcn_global_load_lds(
          (const __attribute__((address_space(1))) void*)(const void*)ga,
          (__attribute__((address_space(3))) void*)(void*)&lA[f * 8], 16, 0, 0);
      __builtin_amdgcn_global_load_lds(
          (const __attribute__((address_space(1))) void*)(const void*)gb,
          (__attribute__((address_space(3))) void*)(void*)&lB[f * 8], 16, 0, 0);
    }
    __syncthreads();

    // ---- compute: 2 k-steps of 32, 16 MFMAs each ----
    #pragma unroll
    for (int kk = 0; kk < 64; kk += 32) {
      bf16x8 af[4], bfr[4];
      #pragma unroll
      for (int i = 0; i < 4; ++i) {
        int cj = (((kk >> 3) + lq) ^ h) << 3;  // de-swizzled chunk offset
        af[i] = *(const bf16x8*)&lA[(wm + i * 16 + lr) * 64 + cj];
      }
      #pragma unroll
      for (int j = 0; j < 4; ++j) {
        int cj = (((kk >> 3) + lq) ^ h) << 3;
        bfr[j] = *(const bf16x8*)&lB[(wn + j * 16 + lr) * 64 + cj];
      }
      #pragma unroll
      for (int i = 0; i < 4; ++i)
        #pragma unroll
        for (int j = 0; j < 4; ++j)
          acc[i][j] = __builtin_amdgcn_mfma_f32_16x16x32_bf16(
              af[i], bfr[j], acc[i][j], 0, 0, 0);
    }
    __syncthreads();
  }

  // ---- epilogue: C/D mapping col=lane&15, row=(lane>>4)*4+reg ----
  #pragma unroll
  for (int i = 0; i < 4; ++i)
    #pragma unroll
    for (int j = 0; j < 4; ++j)
      #pragma unroll
      for (int rr = 0; rr < 4; ++rr) {
        int mm = m0 + wm + i * 16 + lq * 4 + rr;
        int nn = n0 + wn + j * 16 + lr;
        out[(size_t)mm * NDIM + nn] = acc[i][j][rr];
      }
}

extern "C" void kernel_launch(void* const* d_in, const int* in_sizes, int n_in,
                              void* d_out, int out_size, void* d_ws, size_t ws_size,
                              hipStream_t stream) {
  const float* x  = (const float*)d_in[0];   // [4,2048,4096] fp32
  const float* W  = (const float*)d_in[1];   // [4096,4096]
  const float* A  = (const float*)d_in[2];   // [4096,64]
  const float* B  = (const float*)d_in[3];   // [64,4096]
  const float* sv = (const float*)d_in[4];   // [1e6]
  const int*   si = (const int*)d_in[5];     // [2,1e6]
  float* out = (float*)d_out;

  // workspace: S f32 (64MB) | weff bf16 (32MB) | x bf16 (64MB)
  float*  S     = (float*)d_ws;
  bf16_t* weffb = (bf16_t*)(S + (size_t)D_OUT * D_IN);
  bf16_t* xb    = weffb + (size_t)D_OUT * D_IN;

  zero_f32_kernel<<<4096, 256, 0, stream>>>(S, D_OUT * D_IN / 4);
  scatter_sp_kernel<<<(NNZ + 255) / 256, 256, 0, stream>>>(sv, si, S);
  build_weff_fused_kernel<<<dim3(D_IN / 256, D_OUT / 64), 256, 0, stream>>>(W, A, B, S, weffb);
  cvt_bf16_kernel<<<(MTOT * KDIM / 8) / 256, 256, 0, stream>>>(x, xb, MTOT * KDIM / 8);
  gemm_bt_kernel<<<dim3(NDIM / 128, MTOT / 128), 256, 0, stream>>>(xb, weffb, out);
}

// Round 3
// 679.432 us; speedup vs baseline: 1.2052x; 1.0892x over previous
//
#include <hip/hip_runtime.h>

#define D_OUT 4096
#define D_IN  4096
#define RANK  64
#define NNZ   1000000
#define MTOT  8192   // 4*2048
#define KDIM  4096
#define NDIM  4096

typedef __bf16 bf16_t;
typedef __bf16 bf16x8 __attribute__((ext_vector_type(8)));
typedef __bf16 bf16x4 __attribute__((ext_vector_type(4)));
typedef float  f32x4  __attribute__((ext_vector_type(4)));

// ---------------- kernel 1: scatter-add sparse COO into S ----------------
__global__ __launch_bounds__(256) void scatter_sp_kernel(
    const float* __restrict__ vals, const int* __restrict__ idx,
    float* __restrict__ S) {
  int i = blockIdx.x * 256 + threadIdx.x;
  if (i < NNZ) {
    int r = idx[i];
    int c = idx[NNZ + i];
    atomicAdd(&S[(size_t)r * D_IN + c], vals[i]);
  }
}

// ---------------- kernel 2: weffb = bf16(W + A@Bmat + S) ----------------
// Register-blocked: block tile 64(o) x 128(d); thread = 8(o) x 4(d) outputs.
// Per r-step: 8 broadcast ds_read_b32 (2 distinct addrs/wave -> free) +
// 1 global f32x4 of B + 32 fmac. 8x fewer LDS instrs than the R1 version.
__global__ __launch_bounds__(256) void build_weff_fused_kernel(
    const float* __restrict__ W, const float* __restrict__ A,
    const float* __restrict__ B, const float* __restrict__ S,
    bf16_t* __restrict__ outb) {
  __shared__ float sA[64 * 64];
  const int o0 = blockIdx.y * 64;
  const int d0 = blockIdx.x * 128;
  const int t  = threadIdx.x;
  const int td = t & 31;     // d-group
  const int to = t >> 5;     // o-group 0..7
  const int d  = d0 + td * 4;

  #pragma unroll
  for (int i = 0; i < 16; ++i)
    sA[t + i * 256] = A[(size_t)o0 * 64 + t + i * 256];
  __syncthreads();

  f32x4 acc[8] = {};
  for (int r = 0; r < 64; ++r) {
    f32x4 bv = *(const f32x4*)&B[(size_t)r * D_IN + d];
    #pragma unroll
    for (int j = 0; j < 8; ++j) {
      float a = sA[(to * 8 + j) * 64 + r];
      acc[j] += a * bv;
    }
  }

  #pragma unroll
  for (int j = 0; j < 8; ++j) {
    int o = o0 + to * 8 + j;
    size_t idx = (size_t)o * D_IN + d;
    f32x4 wv = *(const f32x4*)&W[idx];
    f32x4 sv = *(const f32x4*)&S[idx];
    f32x4 v  = wv + sv + acc[j];
    bf16x4 ob;
    ob[0] = (bf16_t)v[0]; ob[1] = (bf16_t)v[1];
    ob[2] = (bf16_t)v[2]; ob[3] = (bf16_t)v[3];
    *(bf16x4*)&outb[idx] = ob;
  }
}

// ---------------- kernel 3: fp32 -> bf16 cast (8 elems/thread) ----------------
__global__ __launch_bounds__(256) void cvt_bf16_kernel(
    const float* __restrict__ in, bf16_t* __restrict__ out, int n8) {
  int i = blockIdx.x * 256 + threadIdx.x;
  if (i >= n8) return;
  const f32x4* p = (const f32x4*)in + (size_t)i * 2;
  f32x4 a = p[0], b = p[1];
  bf16x8 o;
  o[0] = (bf16_t)a[0]; o[1] = (bf16_t)a[1]; o[2] = (bf16_t)a[2]; o[3] = (bf16_t)a[3];
  o[4] = (bf16_t)b[0]; o[5] = (bf16_t)b[1]; o[6] = (bf16_t)b[2]; o[7] = (bf16_t)b[3];
  *((bf16x8*)out + i) = o;
}

// ---------------- kernel 4: out[M][N] = Xb[M][K] @ Wb[N][K]^T ----------------
// m97 structure + XOR-swizzled LDS k-chunks (R1: conflicts 1e8 -> 0).
__global__ __launch_bounds__(256) void gemm_bt_kernel(
    const bf16_t* __restrict__ Xb, const bf16_t* __restrict__ Wb,
    float* __restrict__ out) {
  __shared__ bf16_t lA[128 * 64];   // 16 KB
  __shared__ bf16_t lB[128 * 64];   // 16 KB

  const int t    = threadIdx.x;
  const int w    = t >> 6;
  const int lane = t & 63;
  const int m0 = blockIdx.y * 128;
  const int n0 = blockIdx.x * 128;
  const int wm = (w >> 1) * 64;
  const int wn = (w & 1) * 64;
  const int lr = lane & 15;   // fragment row / C col
  const int lq = lane >> 4;   // quad
  const int h  = lr & 7;      // swizzle key

  f32x4 acc[4][4] = {};

  for (int k0 = 0; k0 < KDIM; k0 += 64) {
    #pragma unroll
    for (int j = 0; j < 4; ++j) {
      int f   = j * 256 + t;                  // 0..1023
      int row = f >> 3;                       // 0..127
      int kc  = (((f & 7) ^ (row & 7)) << 3); // swizzled k-chunk, elems
      const bf16_t* ga = Xb + (size_t)(m0 + row) * KDIM + k0 + kc;
      const bf16_t* gb = Wb + (size_t)(n0 + row) * KDIM + k0 + kc;
      __builtin_amdgcn_global_load_lds(
          (const __attribute__((address_space(1))) void*)(const void*)ga,
          (__attribute__((address_space(3))) void*)(void*)&lA[f * 8], 16, 0, 0);
      __builtin_amdgcn_global_load_lds(
          (const __attribute__((address_space(1))) void*)(const void*)gb,
          (__attribute__((address_space(3))) void*)(void*)&lB[f * 8], 16, 0, 0);
    }
    __syncthreads();

    #pragma unroll
    for (int kk = 0; kk < 64; kk += 32) {
      bf16x8 af[4], bfr[4];
      #pragma unroll
      for (int i = 0; i < 4; ++i) {
        int cj = (((kk >> 3) + lq) ^ h) << 3;
        af[i] = *(const bf16x8*)&lA[(wm + i * 16 + lr) * 64 + cj];
      }
      #pragma unroll
      for (int j = 0; j < 4; ++j) {
        int cj = (((kk >> 3) + lq) ^ h) << 3;
        bfr[j] = *(const bf16x8*)&lB[(wn + j * 16 + lr) * 64 + cj];
      }
      #pragma unroll
      for (int i = 0; i < 4; ++i)
        #pragma unroll
        for (int j = 0; j < 4; ++j)
          acc[i][j] = __builtin_amdgcn_mfma_f32_16x16x32_bf16(
              af[i], bfr[j], acc[i][j], 0, 0, 0);
    }
    __syncthreads();
  }

  #pragma unroll
  for (int i = 0; i < 4; ++i)
    #pragma unroll
    for (int j = 0; j < 4; ++j)
      #pragma unroll
      for (int rr = 0; rr < 4; ++rr) {
        int mm = m0 + wm + i * 16 + lq * 4 + rr;
        int nn = n0 + wn + j * 16 + lr;
        out[(size_t)mm * NDIM + nn] = acc[i][j][rr];
      }
}

extern "C" void kernel_launch(void* const* d_in, const int* in_sizes, int n_in,
                              void* d_out, int out_size, void* d_ws, size_t ws_size,
                              hipStream_t stream) {
  const float* x  = (const float*)d_in[0];   // [4,2048,4096] fp32
  const float* W  = (const float*)d_in[1];   // [4096,4096]
  const float* A  = (const float*)d_in[2];   // [4096,64]
  const float* B  = (const float*)d_in[3];   // [64,4096]
  const float* sv = (const float*)d_in[4];   // [1e6]
  const int*   si = (const int*)d_in[5];     // [2,1e6]
  float* out = (float*)d_out;

  // workspace: S f32 (64MB) | weff bf16 (32MB) | x bf16 (64MB)
  float*  S     = (float*)d_ws;
  bf16_t* weffb = (bf16_t*)(S + (size_t)D_OUT * D_IN);
  bf16_t* xb    = weffb + (size_t)D_OUT * D_IN;

  hipMemsetAsync(S, 0, (size_t)D_OUT * D_IN * sizeof(float), stream);
  scatter_sp_kernel<<<(NNZ + 255) / 256, 256, 0, stream>>>(sv, si, S);
  build_weff_fused_kernel<<<dim3(D_IN / 128, D_OUT / 64), 256, 0, stream>>>(W, A, B, S, weffb);
  cvt_bf16_kernel<<<(MTOT * KDIM / 8) / 256, 256, 0, stream>>>(x, xb, MTOT * KDIM / 8);
  gemm_bt_kernel<<<dim3(NDIM / 128, MTOT / 128), 256, 0, stream>>>(xb, weffb, out);
}